// Round 1
// baseline (15063.889 us; speedup 1.0000x reference)
//
#include <hip/hip_runtime.h>
#include <math.h>

// ============================================================================
// RSSM forward on MI355X.
//  - obs MLP + po1_o precompute: parallel MFMA GEMMs (bf16, in-place in ws)
//  - recurrence: 32 persistent workgroups x 16 batch rows, states in LDS,
//    weights pre-shuffled into MFMA B-fragment tiles, streamed from L2.
// ============================================================================

using v8s   = __attribute__((ext_vector_type(8))) short;
using f32x4 = __attribute__((ext_vector_type(4))) float;

#define BN   512
#define TN   128
#define LATN 128

#define AB_S 264   // 256-col LDS activation stride (shorts): +8 pad -> 4-bank row shift
#define SA_S 136   // 128-col stride

// pre-shuffled weight tile bases (1 tile = 16n x 32k bf16 = 1KB = 512 shorts)
#define OBS1_T 0
#define OBS2_T 256
#define PO1O_T 384
#define PO1H_T 512
#define GINS_T 640
#define IH_T   704
#define HH_T   1088
#define PR1_T  1472
#define PR2_T  1600
#define PRM_T  1728
#define PRV_T  1792
#define PO2_T  1856
#define POM_T  1984
#define POV_T  2048
#define TOT_TILES 2112

#define B1_BYTES 33554432UL          // 65536 x 256 bf16
#define KL_OFF   8388608UL           // states elements (512*128*128)

__device__ __forceinline__ unsigned short f2bf(float f){
  union { float f; unsigned u; } v; v.f = f;
  unsigned u = v.u + 0x7fffu + ((v.u >> 16) & 1u);   // RNE
  return (unsigned short)(u >> 16);
}
__device__ __forceinline__ float bf2f(unsigned short s){
  union { unsigned u; float f; } v; v.u = ((unsigned)s) << 16; return v.f;
}
__device__ __forceinline__ float sigm(float x){ return 1.f / (1.f + __expf(-x)); }
__device__ __forceinline__ float tanhx(float x){ return 1.f - 2.f/(__expf(2.f*x) + 1.f); }

#define MFMA16(a,b,c) __builtin_amdgcn_mfma_f32_16x16x32_bf16((a),(b),(c),0,0,0)
#define LDB(tIdx) (*(const v8s*)(wt + ((size_t)(tIdx))*512 + lane*8))

// ---------------------------------------------------------------------------
// Weight shuffle: f32 (N,K) row-major -> bf16 fragment-linear tiles.
// tile (nt,kt): lane l holds W[nt*16+(l&15)][coloff + kt*32 + (l>>4)*8 + j]
// ---------------------------------------------------------------------------
struct ShufArgs {
  const float* src[14];
  int stride[14], coloff[14], ktiles[14], tbase[14], tcnt[14];
};

__global__ __launch_bounds__(64) void shuffle_w(ShufArgs sa, unsigned short* __restrict__ wt)
{
  int tile = blockIdx.x;
  int s = 0;
  while (tile >= sa.tbase[s] + sa.tcnt[s]) s++;
  int lt = tile - sa.tbase[s];
  int kt = lt % sa.ktiles[s];
  int nt = lt / sa.ktiles[s];
  int l  = threadIdx.x;
  int n  = nt*16 + (l & 15);
  int k  = sa.coloff[s] + kt*32 + (l >> 4)*8;
  const float* sp = sa.src[s] + (size_t)n * sa.stride[s] + k;
  unsigned short* dp = wt + (size_t)tile*512 + (size_t)l*8;
  #pragma unroll
  for (int j = 0; j < 8; j++) dp[j] = f2bf(sp[j]);
}

// ---------------------------------------------------------------------------
// Parallel GEMM: out(M x 256) = act(A(M x K) @ W^T + bias), M = 65536.
// 64 rows per block; wave w owns rows w*16..w*16+15, all 256 cols.
// aIsF32: A is f32 (vis_feats) else bf16. Output bf16. In-place safe (rows
// are block-exclusive; staged through LDS before the write).
// ---------------------------------------------------------------------------
__global__ __launch_bounds__(256) void big_gemm(
    const void* __restrict__ Ain, int aIsF32, int K,
    const unsigned short* __restrict__ wt, int tbase,
    const float* __restrict__ bias, int doRelu,
    unsigned short* __restrict__ outB)
{
  __shared__ unsigned short AL[64*AB_S];
  int tid = threadIdx.x, lane = tid & 63, wv = tid >> 6;
  int q = lane >> 4, c16 = lane & 15;
  size_t row0 = (size_t)blockIdx.x * 64;

  f32x4 acc[16];
  #pragma unroll
  for (int nt = 0; nt < 16; nt++) acc[nt] = (f32x4){0.f,0.f,0.f,0.f};

  int nchunk = K >> 8;            // 512 -> 2, 256 -> 1
  int ktT    = K >> 5;            // total ktiles
  for (int cc = 0; cc < nchunk; cc++){
    int r = tid >> 2, c0 = (tid & 3) * 64;
    if (aIsF32){
      const float* A = (const float*)Ain + (row0 + r) * (size_t)K + (size_t)cc*256 + c0;
      #pragma unroll
      for (int ii = 0; ii < 16; ii++){
        float4 x = ((const float4*)A)[ii];
        ushort4 o;
        o.x = f2bf(x.x); o.y = f2bf(x.y); o.z = f2bf(x.z); o.w = f2bf(x.w);
        *(ushort4*)&AL[r*AB_S + c0 + ii*4] = o;
      }
    } else {
      const unsigned short* A = (const unsigned short*)Ain + (row0 + r)*256 + c0;
      #pragma unroll
      for (int ii = 0; ii < 8; ii++)
        *(v8s*)&AL[r*AB_S + c0 + ii*8] = *(const v8s*)(A + ii*8);
    }
    __syncthreads();
    const unsigned short* myA = &AL[wv*16*AB_S];
    #pragma unroll
    for (int kt = 0; kt < 8; kt++){
      v8s af = *(const v8s*)&myA[c16*AB_S + kt*32 + q*8];
      #pragma unroll
      for (int nt = 0; nt < 16; nt++){
        v8s bf = *(const v8s*)(wt + ((size_t)(tbase + nt*ktT + cc*8 + kt))*512 + lane*8);
        acc[nt] = MFMA16(af, bf, acc[nt]);
      }
    }
    __syncthreads();
  }
  #pragma unroll
  for (int nt = 0; nt < 16; nt++){
    int col = nt*16 + c16;
    float b = bias[col];
    #pragma unroll
    for (int i = 0; i < 4; i++){
      float v = acc[nt][i] + b;
      if (doRelu) v = fmaxf(v, 0.f);
      outB[(row0 + wv*16 + q*4 + i)*256 + col] = f2bf(v);
    }
  }
}

// ---------------------------------------------------------------------------
// Recurrent kernel helpers (16 rows, 4 waves; wave w owns 64 cols of N=256)
// ---------------------------------------------------------------------------
__device__ __forceinline__ void stage256(
    const unsigned short* __restrict__ inA,
    const unsigned short* __restrict__ wt, int tbase,
    const float* __restrict__ bias,
    unsigned short* __restrict__ outA, int lane, int wv)
{
  int q = lane >> 4, c16 = lane & 15;
  v8s af[8];
  #pragma unroll
  for (int kt = 0; kt < 8; kt++) af[kt] = *(const v8s*)&inA[c16*AB_S + kt*32 + q*8];
  #pragma unroll
  for (int ntl = 0; ntl < 4; ntl++){
    int nt = wv*4 + ntl;
    f32x4 acc = (f32x4){0.f,0.f,0.f,0.f};
    #pragma unroll
    for (int kt = 0; kt < 8; kt++) acc = MFMA16(af[kt], LDB(tbase + nt*8 + kt), acc);
    int col = nt*16 + c16;
    float b = bias[col];
    #pragma unroll
    for (int i = 0; i < 4; i++)
      outA[(q*4 + i)*AB_S + col] = f2bf(fmaxf(acc[i] + b, 0.f));
  }
}

// posterior mid1: relu(h @ Wpo1h^T + po1_o[row,t])  (b_po1 folded into po1_o)
__device__ __forceinline__ void stage256_add(
    const unsigned short* __restrict__ inA,
    const unsigned short* __restrict__ wt, int tbase,
    const unsigned short* __restrict__ pAdd,   // + r*(TN*256) + col
    unsigned short* __restrict__ outA, int lane, int wv)
{
  int q = lane >> 4, c16 = lane & 15;
  v8s af[8];
  #pragma unroll
  for (int kt = 0; kt < 8; kt++) af[kt] = *(const v8s*)&inA[c16*AB_S + kt*32 + q*8];
  #pragma unroll
  for (int ntl = 0; ntl < 4; ntl++){
    int nt = wv*4 + ntl;
    f32x4 acc = (f32x4){0.f,0.f,0.f,0.f};
    #pragma unroll
    for (int kt = 0; kt < 8; kt++) acc = MFMA16(af[kt], LDB(tbase + nt*8 + kt), acc);
    int col = nt*16 + c16;
    #pragma unroll
    for (int i = 0; i < 4; i++){
      float v = acc[i] + bf2f(pAdd[(size_t)(q*4 + i)*(TN*256) + col]);
      outA[(q*4 + i)*AB_S + col] = f2bf(fmaxf(v, 0.f));
    }
  }
}

__device__ __forceinline__ void prior_heads(
    const unsigned short* __restrict__ AB2,
    const unsigned short* __restrict__ wt,
    const float* __restrict__ b_prm, const float* __restrict__ b_prv,
    float* __restrict__ mupF, float* __restrict__ varpF, int lane, int wv)
{
  int q = lane >> 4, c16 = lane & 15;
  v8s af[8];
  #pragma unroll
  for (int kt = 0; kt < 8; kt++) af[kt] = *(const v8s*)&AB2[c16*AB_S + kt*32 + q*8];
  #pragma unroll
  for (int ntl = 0; ntl < 2; ntl++){
    int nt = wv*2 + ntl;
    f32x4 am = (f32x4){0.f,0.f,0.f,0.f}, av = (f32x4){0.f,0.f,0.f,0.f};
    #pragma unroll
    for (int kt = 0; kt < 8; kt++){
      am = MFMA16(af[kt], LDB(PRM_T + nt*8 + kt), am);
      av = MFMA16(af[kt], LDB(PRV_T + nt*8 + kt), av);
    }
    int col = nt*16 + c16;
    float bm = b_prm[col], bv = b_prv[col];
    #pragma unroll
    for (int i = 0; i < 4; i++){
      int r = q*4 + i;
      mupF [r*LATN + col] = am[i] + bm;
      varpF[r*LATN + col] = __expf(av[i] + bv) + 0.01f;
    }
  }
}

__device__ __forceinline__ void post_heads(
    const unsigned short* __restrict__ AB2,
    const unsigned short* __restrict__ wt,
    const float* __restrict__ b_pom, const float* __restrict__ b_pov,
    const float* __restrict__ mupF, const float* __restrict__ varpF,
    unsigned short* __restrict__ sA,
    float* __restrict__ out, const float* __restrict__ noise,
    float* __restrict__ klRow,
    int b0, int tN, int tS, int doKl, int lane, int wv)
{
  int q = lane >> 4, c16 = lane & 15;
  v8s af[8];
  #pragma unroll
  for (int kt = 0; kt < 8; kt++) af[kt] = *(const v8s*)&AB2[c16*AB_S + kt*32 + q*8];
  float kv[4] = {0.f,0.f,0.f,0.f};
  #pragma unroll
  for (int ntl = 0; ntl < 2; ntl++){
    int nt = wv*2 + ntl;
    f32x4 am = (f32x4){0.f,0.f,0.f,0.f}, av = (f32x4){0.f,0.f,0.f,0.f};
    #pragma unroll
    for (int kt = 0; kt < 8; kt++){
      am = MFMA16(af[kt], LDB(POM_T + nt*8 + kt), am);
      av = MFMA16(af[kt], LDB(POV_T + nt*8 + kt), av);
    }
    int col = nt*16 + c16;
    float bm = b_pom[col], bv = b_pov[col];
    #pragma unroll
    for (int i = 0; i < 4; i++){
      int r = q*4 + i;
      float mq = am[i] + bm;
      float vq = __expf(av[i] + bv) + 0.01f;
      float ep = noise[((size_t)tN*BN + b0 + r)*LATN + col];
      float sv = mq + sqrtf(vq)*ep;
      sA[r*SA_S + col] = f2bf(sv);
      out[((size_t)(b0 + r)*TN + tS)*LATN + col] = sv;
      if (doKl){
        float mp = mupF[r*LATN + col], vp = varpF[r*LATN + col];
        float d = mq - mp;
        kv[i] += __logf(vp) - __logf(vq) + (vq + d*d)/vp - 1.f;
      }
    }
  }
  if (doKl){
    #pragma unroll
    for (int i = 0; i < 4; i++){
      float v = kv[i];
      #pragma unroll
      for (int m = 1; m < 16; m <<= 1) v += __shfl_xor(v, m, 64);
      if (c16 == 0) atomicAdd(&klRow[q*4 + i], v);
    }
  }
}

// ---------------------------------------------------------------------------
// Persistent recurrence: block g owns batch rows g*16..g*16+15 for all steps.
// ---------------------------------------------------------------------------
__global__ __launch_bounds__(256, 1) void rssm_rnn(
    const unsigned short* __restrict__ wt,
    const unsigned short* __restrict__ Pbuf,      // po1_o bf16 (B*T x 256)
    const float* __restrict__ actions, const float* __restrict__ noise,
    const float* __restrict__ w_gin,  const float* __restrict__ b_gin,
    const float* __restrict__ b_ih,   const float* __restrict__ b_hh,
    const float* __restrict__ b_pr1,  const float* __restrict__ b_pr2,
    const float* __restrict__ b_prm,  const float* __restrict__ b_prv,
    const float* __restrict__ b_po2,  const float* __restrict__ b_pom,
    const float* __restrict__ b_pov,
    float* __restrict__ out)
{
  __shared__ unsigned short sA [16*SA_S];
  __shared__ unsigned short hA [16*AB_S];
  __shared__ unsigned short AB1[16*AB_S];
  __shared__ unsigned short AB2[16*AB_S];
  __shared__ float hF   [16*256];
  __shared__ float mupF [16*LATN];
  __shared__ float varpF[16*LATN];
  __shared__ float aF   [16*8];
  __shared__ float klRow[16];

  int tid = threadIdx.x, lane = tid & 63, wv = tid >> 6;
  int q = lane >> 4, c16 = lane & 15;
  int b0 = blockIdx.x * 16;

  for (int i = tid; i < 16*256; i += 256) hF[i] = 0.f;
  for (int i = tid; i < 16*AB_S; i += 256) hA[i] = 0;

  // ---- s0: posterior with belief = 0 -> mid1 = relu(po1_o[:, t=0]) ----
  for (int i = tid; i < 16*256; i += 256){
    int r = i >> 8, c = i & 255;
    float v = bf2f(Pbuf[((size_t)(b0 + r)*TN + 0)*256 + c]);
    AB1[r*AB_S + c] = f2bf(fmaxf(v, 0.f));
  }
  __syncthreads();
  stage256(AB1, wt, PO2_T, b_po2, AB2, lane, wv);
  __syncthreads();
  post_heads(AB2, wt, b_pom, b_pov, mupF, varpF, sA, out, noise, klRow, b0, 0, 0, 0, lane, wv);
  __syncthreads();

  for (int t = 0; t < TN-1; t++){
    if (tid < 128) aF[tid] = actions[((size_t)(b0 + (tid>>3))*127 + t)*8 + (tid & 7)];
    __syncthreads();

    // ---- g = relu(s @ WginS^T + a @ WginA^T + b_gin) -> AB1 ----
    {
      v8s af[4];
      #pragma unroll
      for (int kt = 0; kt < 4; kt++) af[kt] = *(const v8s*)&sA[c16*SA_S + kt*32 + q*8];
      #pragma unroll
      for (int ntl = 0; ntl < 4; ntl++){
        int nt = wv*4 + ntl;
        f32x4 acc = (f32x4){0.f,0.f,0.f,0.f};
        #pragma unroll
        for (int kt = 0; kt < 4; kt++) acc = MFMA16(af[kt], LDB(GINS_T + nt*4 + kt), acc);
        int col = nt*16 + c16;
        float bg = b_gin[col];
        float wa[8];
        #pragma unroll
        for (int j = 0; j < 8; j++) wa[j] = w_gin[col*136 + 128 + j];
        #pragma unroll
        for (int i = 0; i < 4; i++){
          int r = q*4 + i;
          float v = acc[i] + bg;
          #pragma unroll
          for (int j = 0; j < 8; j++) v += aF[r*8 + j]*wa[j];
          AB1[r*AB_S + col] = f2bf(fmaxf(v, 0.f));
        }
      }
    }
    __syncthreads();

    // ---- fused GRU: gi = g@Wih^T, gh = h@Whh^T, gates in registers ----
    {
      v8s ag[8], ah[8];
      #pragma unroll
      for (int kt = 0; kt < 8; kt++){
        ag[kt] = *(const v8s*)&AB1[c16*AB_S + kt*32 + q*8];
        ah[kt] = *(const v8s*)&hA [c16*AB_S + kt*32 + q*8];
      }
      __syncthreads();   // everyone captured old h before hA is overwritten
      f32x4 acc[6][4];
      #pragma unroll
      for (int s = 0; s < 6; s++)
        #pragma unroll
        for (int ntl = 0; ntl < 4; ntl++) acc[s][ntl] = (f32x4){0.f,0.f,0.f,0.f};
      #pragma unroll
      for (int s = 0; s < 6; s++){
        int tb = (s < 3) ? IH_T : HH_T;
        #pragma unroll
        for (int ntl = 0; ntl < 4; ntl++){
          int nt = (s % 3)*16 + wv*4 + ntl;
          #pragma unroll
          for (int kt = 0; kt < 8; kt++)
            acc[s][ntl] = MFMA16((s < 3 ? ag[kt] : ah[kt]), LDB(tb + nt*8 + kt), acc[s][ntl]);
        }
      }
      #pragma unroll
      for (int ntl = 0; ntl < 4; ntl++){
        int col = wv*64 + ntl*16 + c16;
        float bir = b_ih[col], biz = b_ih[256+col], bin = b_ih[512+col];
        float bhr = b_hh[col], bhz = b_hh[256+col], bhn = b_hh[512+col];
        #pragma unroll
        for (int i = 0; i < 4; i++){
          int r = q*4 + i;
          float ir = acc[0][ntl][i] + bir, iz = acc[1][ntl][i] + biz, in2 = acc[2][ntl][i] + bin;
          float hr = acc[3][ntl][i] + bhr, hz = acc[4][ntl][i] + bhz, hn  = acc[5][ntl][i] + bhn;
          float rg = sigm(ir + hr);
          float zg = sigm(iz + hz);
          float ng = tanhx(in2 + rg*hn);
          float ho = hF[r*256 + col];
          float hv = (1.f - zg)*ng + zg*ho;
          hF[r*256 + col] = hv;
          hA[r*AB_S + col] = f2bf(hv);
        }
      }
    }
    __syncthreads();

    // ---- prior ----
    stage256(hA,  wt, PR1_T, b_pr1, AB1, lane, wv);
    __syncthreads();
    stage256(AB1, wt, PR2_T, b_pr2, AB2, lane, wv);
    __syncthreads();
    prior_heads(AB2, wt, b_prm, b_prv, mupF, varpF, lane, wv);
    __syncthreads();

    // ---- posterior ----
    stage256_add(hA, wt, PO1H_T, Pbuf + ((size_t)b0*TN + (t+1))*256, AB1, lane, wv);
    if (tid < 16) klRow[tid] = 0.f;
    __syncthreads();
    stage256(AB1, wt, PO2_T, b_po2, AB2, lane, wv);
    __syncthreads();
    post_heads(AB2, wt, b_pom, b_pov, mupF, varpF, sA, out, noise, klRow,
               b0, t+1, t+1, 1, lane, wv);
    __syncthreads();
    if (tid < 16) out[KL_OFF + (size_t)(b0 + tid)*127 + t] = 0.5f*klRow[tid];
  }
}

// ---------------------------------------------------------------------------
extern "C" void kernel_launch(void* const* d_in, const int* in_sizes, int n_in,
                              void* d_out, int out_size, void* d_ws, size_t ws_size,
                              hipStream_t stream)
{
  (void)in_sizes; (void)n_in; (void)out_size; (void)ws_size;
  const float* vis    = (const float*)d_in[0];
  const float* acts   = (const float*)d_in[1];
  const float* noise  = (const float*)d_in[2];
  const float* w_obs1 = (const float*)d_in[3];
  const float* b_obs1 = (const float*)d_in[4];
  const float* w_obs2 = (const float*)d_in[5];
  const float* b_obs2 = (const float*)d_in[6];
  const float* w_gin  = (const float*)d_in[7];
  const float* b_gin  = (const float*)d_in[8];
  const float* w_ih   = (const float*)d_in[9];
  const float* w_hh   = (const float*)d_in[10];
  const float* b_ih   = (const float*)d_in[11];
  const float* b_hh   = (const float*)d_in[12];
  const float* w_pr1  = (const float*)d_in[13];
  const float* b_pr1  = (const float*)d_in[14];
  const float* w_pr2  = (const float*)d_in[15];
  const float* b_pr2  = (const float*)d_in[16];
  const float* w_prm  = (const float*)d_in[17];
  const float* b_prm  = (const float*)d_in[18];
  const float* w_prv  = (const float*)d_in[19];
  const float* b_prv  = (const float*)d_in[20];
  const float* w_po1  = (const float*)d_in[21];
  const float* b_po1  = (const float*)d_in[22];
  const float* w_po2  = (const float*)d_in[23];
  const float* b_po2  = (const float*)d_in[24];
  const float* w_pom  = (const float*)d_in[25];
  const float* b_pom  = (const float*)d_in[26];
  const float* w_pov  = (const float*)d_in[27];
  const float* b_pov  = (const float*)d_in[28];

  unsigned short* B1 = (unsigned short*)d_ws;                       // 65536x256 bf16
  unsigned short* WT = (unsigned short*)((char*)d_ws + B1_BYTES);   // shuffled tiles

  ShufArgs sa;
  const float* srcs[14] = {w_obs1, w_obs2, w_po1, w_po1, w_gin, w_ih, w_hh,
                           w_pr1, w_pr2, w_prm, w_prv, w_po2, w_pom, w_pov};
  const int strides[14] = {512,256,512,512,136,256,256,256,256,256,256,256,256,256};
  const int coloffs[14] = {0,0,256,0,0,0,0,0,0,0,0,0,0,0};
  const int ktl[14]     = {16,8,8,8,4,8,8,8,8,8,8,8,8,8};
  const int tbas[14]    = {OBS1_T,OBS2_T,PO1O_T,PO1H_T,GINS_T,IH_T,HH_T,
                           PR1_T,PR2_T,PRM_T,PRV_T,PO2_T,POM_T,POV_T};
  const int tcnt[14]    = {256,128,128,128,64,384,384,128,128,64,64,128,64,64};
  for (int i = 0; i < 14; i++){
    sa.src[i] = srcs[i]; sa.stride[i] = strides[i]; sa.coloff[i] = coloffs[i];
    sa.ktiles[i] = ktl[i]; sa.tbase[i] = tbas[i]; sa.tcnt[i] = tcnt[i];
  }
  shuffle_w<<<TOT_TILES, 64, 0, stream>>>(sa, WT);

  // obs MLP + po1_o, all in-place in B1 (rows are block-exclusive)
  big_gemm<<<1024, 256, 0, stream>>>(vis, 1, 512, WT, OBS1_T, b_obs1, 1, B1);
  big_gemm<<<1024, 256, 0, stream>>>(B1,  0, 256, WT, OBS2_T, b_obs2, 1, B1);
  big_gemm<<<1024, 256, 0, stream>>>(B1,  0, 256, WT, PO1O_T, b_po1,  0, B1);

  rssm_rnn<<<32, 256, 0, stream>>>(WT, B1, acts, noise, w_gin, b_gin, b_ih, b_hh,
                                   b_pr1, b_pr2, b_prm, b_prv, b_po2, b_pom, b_pov,
                                   (float*)d_out);
}

// Round 2
// 6913.853 us; speedup vs baseline: 2.1788x; 2.1788x over previous
//
#include <hip/hip_runtime.h>
#include <math.h>

// ============================================================================
// RSSM forward on MI355X.
// Round 2: recurrent kernel widened to 1024 threads (16 waves/CU, 4/SIMD) to
// hide weight-stream latency; per-wave N-strips shrunk 4x; heads split into
// 16 (matrix x nt) tasks with LDS exchange; KL via per-row wave reduction
// (no atomics); nontemporal hints on streaming traffic (Pbuf/noise/out/act)
// to keep the 2.1 MB weight set L2-resident.
// ============================================================================

using v8s   = __attribute__((ext_vector_type(8))) short;
using f32x4 = __attribute__((ext_vector_type(4))) float;

#define BN   512
#define TN   128
#define LATN 128

#define AB_S 264   // 256-col LDS activation stride (shorts)
#define SA_S 136   // 128-col stride

// pre-shuffled weight tile bases (1 tile = 16n x 32k bf16 = 1KB = 512 shorts)
#define OBS1_T 0
#define OBS2_T 256
#define PO1O_T 384
#define PO1H_T 512
#define GINS_T 640
#define IH_T   704
#define HH_T   1088
#define PR1_T  1472
#define PR2_T  1600
#define PRM_T  1728
#define PRV_T  1792
#define PO2_T  1856
#define POM_T  1984
#define POV_T  2048
#define TOT_TILES 2112

#define B1_BYTES 33554432UL          // 65536 x 256 bf16
#define KL_OFF   8388608UL           // states elements (512*128*128)

__device__ __forceinline__ unsigned short f2bf(float f){
  union { float f; unsigned u; } v; v.f = f;
  unsigned u = v.u + 0x7fffu + ((v.u >> 16) & 1u);   // RNE
  return (unsigned short)(u >> 16);
}
__device__ __forceinline__ float bf2f(unsigned short s){
  union { unsigned u; float f; } v; v.u = ((unsigned)s) << 16; return v.f;
}
__device__ __forceinline__ float sigm(float x){ return 1.f / (1.f + __expf(-x)); }
__device__ __forceinline__ float tanhx(float x){ return 1.f - 2.f/(__expf(2.f*x) + 1.f); }

#define MFMA16(a,b,c) __builtin_amdgcn_mfma_f32_16x16x32_bf16((a),(b),(c),0,0,0)
#define LDB(tIdx) (*(const v8s*)(wt + ((size_t)(tIdx))*512 + lane*8))

// ---------------------------------------------------------------------------
// Weight shuffle: f32 (N,K) row-major -> bf16 fragment-linear tiles.
// ---------------------------------------------------------------------------
struct ShufArgs {
  const float* src[14];
  int stride[14], coloff[14], ktiles[14], tbase[14], tcnt[14];
};

__global__ __launch_bounds__(64) void shuffle_w(ShufArgs sa, unsigned short* __restrict__ wt)
{
  int tile = blockIdx.x;
  int s = 0;
  while (tile >= sa.tbase[s] + sa.tcnt[s]) s++;
  int lt = tile - sa.tbase[s];
  int kt = lt % sa.ktiles[s];
  int nt = lt / sa.ktiles[s];
  int l  = threadIdx.x;
  int n  = nt*16 + (l & 15);
  int k  = sa.coloff[s] + kt*32 + (l >> 4)*8;
  const float* sp = sa.src[s] + (size_t)n * sa.stride[s] + k;
  unsigned short* dp = wt + (size_t)tile*512 + (size_t)l*8;
  #pragma unroll
  for (int j = 0; j < 8; j++) dp[j] = f2bf(sp[j]);
}

// ---------------------------------------------------------------------------
// Parallel GEMM for obs MLP / po1_o precompute (unchanged from round 1).
// ---------------------------------------------------------------------------
__global__ __launch_bounds__(256) void big_gemm(
    const void* __restrict__ Ain, int aIsF32, int K,
    const unsigned short* __restrict__ wt, int tbase,
    const float* __restrict__ bias, int doRelu,
    unsigned short* __restrict__ outB)
{
  __shared__ unsigned short AL[64*AB_S];
  int tid = threadIdx.x, lane = tid & 63, wv = tid >> 6;
  int q = lane >> 4, c16 = lane & 15;
  size_t row0 = (size_t)blockIdx.x * 64;

  f32x4 acc[16];
  #pragma unroll
  for (int nt = 0; nt < 16; nt++) acc[nt] = (f32x4){0.f,0.f,0.f,0.f};

  int nchunk = K >> 8;
  int ktT    = K >> 5;
  for (int cc = 0; cc < nchunk; cc++){
    int r = tid >> 2, c0 = (tid & 3) * 64;
    if (aIsF32){
      const float* A = (const float*)Ain + (row0 + r) * (size_t)K + (size_t)cc*256 + c0;
      #pragma unroll
      for (int ii = 0; ii < 16; ii++){
        float4 x = ((const float4*)A)[ii];
        ushort4 o;
        o.x = f2bf(x.x); o.y = f2bf(x.y); o.z = f2bf(x.z); o.w = f2bf(x.w);
        *(ushort4*)&AL[r*AB_S + c0 + ii*4] = o;
      }
    } else {
      const unsigned short* A = (const unsigned short*)Ain + (row0 + r)*256 + c0;
      #pragma unroll
      for (int ii = 0; ii < 8; ii++)
        *(v8s*)&AL[r*AB_S + c0 + ii*8] = *(const v8s*)(A + ii*8);
    }
    __syncthreads();
    const unsigned short* myA = &AL[wv*16*AB_S];
    #pragma unroll
    for (int kt = 0; kt < 8; kt++){
      v8s af = *(const v8s*)&myA[c16*AB_S + kt*32 + q*8];
      #pragma unroll
      for (int nt = 0; nt < 16; nt++){
        v8s bf = *(const v8s*)(wt + ((size_t)(tbase + nt*ktT + cc*8 + kt))*512 + lane*8);
        acc[nt] = MFMA16(af, bf, acc[nt]);
      }
    }
    __syncthreads();
  }
  #pragma unroll
  for (int nt = 0; nt < 16; nt++){
    int col = nt*16 + c16;
    float b = bias[col];
    #pragma unroll
    for (int i = 0; i < 4; i++){
      float v = acc[nt][i] + b;
      if (doRelu) v = fmaxf(v, 0.f);
      outB[(row0 + wv*16 + q*4 + i)*256 + col] = f2bf(v);
    }
  }
}

// ---------------------------------------------------------------------------
// Recurrent helpers: 16 rows x 256 cols, 16 waves; wave wv owns nt = wv.
// ---------------------------------------------------------------------------
__device__ __forceinline__ void stage256(
    const unsigned short* __restrict__ inA,
    const unsigned short* __restrict__ wt, int tbase,
    const float* __restrict__ bias,
    unsigned short* __restrict__ outA, int lane, int wv)
{
  int q = lane >> 4, c16 = lane & 15;
  v8s af[8];
  #pragma unroll
  for (int kt = 0; kt < 8; kt++) af[kt] = *(const v8s*)&inA[c16*AB_S + kt*32 + q*8];
  int nt = wv;
  f32x4 acc = (f32x4){0.f,0.f,0.f,0.f};
  #pragma unroll
  for (int kt = 0; kt < 8; kt++) acc = MFMA16(af[kt], LDB(tbase + nt*8 + kt), acc);
  int col = nt*16 + c16;
  float b = bias[col];
  #pragma unroll
  for (int i = 0; i < 4; i++)
    outA[(q*4 + i)*AB_S + col] = f2bf(fmaxf(acc[i] + b, 0.f));
}

// posterior mid1: relu(h @ Wpo1h^T + po1_o[row,t])  (b_po1 folded into po1_o)
__device__ __forceinline__ void stage256_add(
    const unsigned short* __restrict__ inA,
    const unsigned short* __restrict__ wt, int tbase,
    const unsigned short* __restrict__ pAdd,   // + r*(TN*256) + col
    unsigned short* __restrict__ outA, int lane, int wv)
{
  int q = lane >> 4, c16 = lane & 15;
  v8s af[8];
  #pragma unroll
  for (int kt = 0; kt < 8; kt++) af[kt] = *(const v8s*)&inA[c16*AB_S + kt*32 + q*8];
  int nt = wv;
  f32x4 acc = (f32x4){0.f,0.f,0.f,0.f};
  #pragma unroll
  for (int kt = 0; kt < 8; kt++) acc = MFMA16(af[kt], LDB(tbase + nt*8 + kt), acc);
  int col = nt*16 + c16;
  #pragma unroll
  for (int i = 0; i < 4; i++){
    float v = acc[i] + bf2f(__builtin_nontemporal_load(
                 &pAdd[(size_t)(q*4 + i)*(TN*256) + col]));
    outA[(q*4 + i)*AB_S + col] = f2bf(fmaxf(v, 0.f));
  }
}

// heads: 16 tasks = {matrix mu/var} x {nt 0..7}; K = 256 (from AB2).
// mu-task writes raw mu+b; var-task writes exp(.)+0.01.
__device__ __forceinline__ void heads16(
    const unsigned short* __restrict__ AB2,
    const unsigned short* __restrict__ wt, int tM, int tV,
    const float* __restrict__ bM, const float* __restrict__ bV,
    float* __restrict__ muF, float* __restrict__ varF, int lane, int wv)
{
  int q = lane >> 4, c16 = lane & 15;
  v8s af[8];
  #pragma unroll
  for (int kt = 0; kt < 8; kt++) af[kt] = *(const v8s*)&AB2[c16*AB_S + kt*32 + q*8];
  __syncthreads();                 // everyone captured AB2 before overlay writes
  int mtx = wv >> 3, nt = wv & 7;
  int tb  = mtx ? tV : tM;
  f32x4 acc = (f32x4){0.f,0.f,0.f,0.f};
  #pragma unroll
  for (int kt = 0; kt < 8; kt++) acc = MFMA16(af[kt], LDB(tb + nt*8 + kt), acc);
  int col = nt*16 + c16;
  float b = mtx ? bV[col] : bM[col];
  float* dst = mtx ? varF : muF;
  #pragma unroll
  for (int i = 0; i < 4; i++){
    float v = acc[i] + b;
    if (mtx) v = __expf(v) + 0.01f;
    dst[(q*4 + i)*LATN + col] = v;
  }
}

// ---------------------------------------------------------------------------
// Persistent recurrence: block g owns batch rows g*16..g*16+15 for all steps.
// 1024 threads = 16 waves (4 per SIMD) for latency hiding.
// ---------------------------------------------------------------------------
__global__ __launch_bounds__(1024, 4) void rssm_rnn(
    const unsigned short* __restrict__ wt,
    const unsigned short* __restrict__ Pbuf,      // po1_o bf16 (B*T x 256)
    const float* __restrict__ actions, const float* __restrict__ noise,
    const float* __restrict__ w_gin,  const float* __restrict__ b_gin,
    const float* __restrict__ b_ih,   const float* __restrict__ b_hh,
    const float* __restrict__ b_pr1,  const float* __restrict__ b_pr2,
    const float* __restrict__ b_prm,  const float* __restrict__ b_prv,
    const float* __restrict__ b_po2,  const float* __restrict__ b_pom,
    const float* __restrict__ b_pov,
    float* __restrict__ out)
{
  __shared__ unsigned short sA [16*SA_S];
  __shared__ unsigned short hA [16*AB_S];
  __shared__ unsigned short AB1[16*AB_S];   // also overlaid as muq (f32 16x128)
  __shared__ unsigned short AB2[16*AB_S];   // also overlaid as varq
  __shared__ float hF   [16*256];
  __shared__ float mupF [16*LATN];
  __shared__ float varpF[16*LATN];
  __shared__ float aF   [16*8];

  float* muqF  = (float*)AB1;
  float* varqF = (float*)AB2;

  int tid = threadIdx.x, lane = tid & 63, wv = tid >> 6;
  int q = lane >> 4, c16 = lane & 15;
  int b0 = blockIdx.x * 16;

  for (int i = tid; i < 16*256; i += 1024) hF[i] = 0.f;
  for (int i = tid; i < 16*AB_S; i += 1024) hA[i] = 0;

  // ---- s0: posterior with belief = 0 -> mid1 = relu(po1_o[:, t=0]) ----
  for (int i = tid; i < 16*256; i += 1024){
    int r = i >> 8, c = i & 255;
    float v = bf2f(__builtin_nontemporal_load(&Pbuf[((size_t)(b0 + r)*TN + 0)*256 + c]));
    AB1[r*AB_S + c] = f2bf(fmaxf(v, 0.f));
  }
  __syncthreads();
  stage256(AB1, wt, PO2_T, b_po2, AB2, lane, wv);
  __syncthreads();
  heads16(AB2, wt, POM_T, POV_T, b_pom, b_pov, muqF, varqF, lane, wv);
  __syncthreads();
  // sample s0 (no KL): wave wv owns row wv
  {
    int r = wv;
    #pragma unroll
    for (int ii = 0; ii < 2; ii++){
      int c = lane + ii*64;
      float mq = muqF[r*LATN + c], vq = varqF[r*LATN + c];
      float ep = __builtin_nontemporal_load(&noise[((size_t)0*BN + b0 + r)*LATN + c]);
      float sv = mq + sqrtf(vq)*ep;
      sA[r*SA_S + c] = f2bf(sv);
      __builtin_nontemporal_store(sv, &out[((size_t)(b0 + r)*TN + 0)*LATN + c]);
    }
  }
  __syncthreads();

  for (int t = 0; t < TN-1; t++){
    if (tid < 128)
      aF[tid] = __builtin_nontemporal_load(
          &actions[((size_t)(b0 + (tid>>3))*127 + t)*8 + (tid & 7)]);
    __syncthreads();

    // ---- g = relu(s @ WginS^T + a @ WginA^T + b_gin) -> AB1 ----
    {
      v8s af[4];
      #pragma unroll
      for (int kt = 0; kt < 4; kt++) af[kt] = *(const v8s*)&sA[c16*SA_S + kt*32 + q*8];
      int nt = wv;
      f32x4 acc = (f32x4){0.f,0.f,0.f,0.f};
      #pragma unroll
      for (int kt = 0; kt < 4; kt++) acc = MFMA16(af[kt], LDB(GINS_T + nt*4 + kt), acc);
      int col = nt*16 + c16;
      float bg = b_gin[col];
      float wa[8];
      #pragma unroll
      for (int j = 0; j < 8; j++) wa[j] = w_gin[col*136 + 128 + j];
      #pragma unroll
      for (int i = 0; i < 4; i++){
        int r = q*4 + i;
        float v = acc[i] + bg;
        #pragma unroll
        for (int j = 0; j < 8; j++) v += aF[r*8 + j]*wa[j];
        AB1[r*AB_S + col] = f2bf(fmaxf(v, 0.f));
      }
    }
    __syncthreads();

    // ---- fused GRU: gi = g@Wih^T, gh = h@Whh^T, gates in registers ----
    {
      v8s ag[8], ah[8];
      #pragma unroll
      for (int kt = 0; kt < 8; kt++){
        ag[kt] = *(const v8s*)&AB1[c16*AB_S + kt*32 + q*8];
        ah[kt] = *(const v8s*)&hA [c16*AB_S + kt*32 + q*8];
      }
      __syncthreads();   // everyone captured old h before hA is overwritten
      f32x4 acc[6];
      #pragma unroll
      for (int s = 0; s < 6; s++) acc[s] = (f32x4){0.f,0.f,0.f,0.f};
      #pragma unroll
      for (int s = 0; s < 6; s++){
        int tb = (s < 3) ? IH_T : HH_T;
        int nt = (s % 3)*16 + wv;
        #pragma unroll
        for (int kt = 0; kt < 8; kt++)
          acc[s] = MFMA16((s < 3 ? ag[kt] : ah[kt]), LDB(tb + nt*8 + kt), acc[s]);
      }
      int col = wv*16 + c16;
      float bir = b_ih[col], biz = b_ih[256+col], bin = b_ih[512+col];
      float bhr = b_hh[col], bhz = b_hh[256+col], bhn = b_hh[512+col];
      #pragma unroll
      for (int i = 0; i < 4; i++){
        int r = q*4 + i;
        float ir = acc[0][i] + bir, iz = acc[1][i] + biz, in2 = acc[2][i] + bin;
        float hr = acc[3][i] + bhr, hz = acc[4][i] + bhz, hn  = acc[5][i] + bhn;
        float rg = sigm(ir + hr);
        float zg = sigm(iz + hz);
        float ng = tanhx(in2 + rg*hn);
        float ho = hF[r*256 + col];
        float hv = (1.f - zg)*ng + zg*ho;
        hF[r*256 + col] = hv;
        hA[r*AB_S + col] = f2bf(hv);
      }
    }
    __syncthreads();

    // ---- prior ----
    stage256(hA,  wt, PR1_T, b_pr1, AB1, lane, wv);
    __syncthreads();
    stage256(AB1, wt, PR2_T, b_pr2, AB2, lane, wv);
    __syncthreads();
    heads16(AB2, wt, PRM_T, PRV_T, b_prm, b_prv, mupF, varpF, lane, wv);
    __syncthreads();

    // ---- posterior ----
    stage256_add(hA, wt, PO1H_T, Pbuf + ((size_t)b0*TN + (t+1))*256, AB1, lane, wv);
    __syncthreads();
    stage256(AB1, wt, PO2_T, b_po2, AB2, lane, wv);
    __syncthreads();
    heads16(AB2, wt, POM_T, POV_T, b_pom, b_pov, muqF, varqF, lane, wv);
    __syncthreads();

    // ---- sample + KL: wave wv owns batch row wv ----
    {
      int r = wv;
      float kv = 0.f;
      #pragma unroll
      for (int ii = 0; ii < 2; ii++){
        int c = lane + ii*64;
        float mq = muqF[r*LATN + c], vq = varqF[r*LATN + c];
        float ep = __builtin_nontemporal_load(
            &noise[((size_t)(t+1)*BN + b0 + r)*LATN + c]);
        float sv = mq + sqrtf(vq)*ep;
        sA[r*SA_S + c] = f2bf(sv);
        __builtin_nontemporal_store(sv, &out[((size_t)(b0 + r)*TN + (t+1))*LATN + c]);
        float mp = mupF[r*LATN + c], vp = varpF[r*LATN + c];
        float d = mq - mp;
        kv += __logf(vp) - __logf(vq) + (vq + d*d)/vp - 1.f;
      }
      #pragma unroll
      for (int m = 1; m < 64; m <<= 1) kv += __shfl_xor(kv, m, 64);
      if (lane == 0)
        __builtin_nontemporal_store(0.5f*kv, &out[KL_OFF + (size_t)(b0 + r)*127 + t]);
    }
    __syncthreads();
  }
}

// ---------------------------------------------------------------------------
extern "C" void kernel_launch(void* const* d_in, const int* in_sizes, int n_in,
                              void* d_out, int out_size, void* d_ws, size_t ws_size,
                              hipStream_t stream)
{
  (void)in_sizes; (void)n_in; (void)out_size; (void)ws_size;
  const float* vis    = (const float*)d_in[0];
  const float* acts   = (const float*)d_in[1];
  const float* noise  = (const float*)d_in[2];
  const float* w_obs1 = (const float*)d_in[3];
  const float* b_obs1 = (const float*)d_in[4];
  const float* w_obs2 = (const float*)d_in[5];
  const float* b_obs2 = (const float*)d_in[6];
  const float* w_gin  = (const float*)d_in[7];
  const float* b_gin  = (const float*)d_in[8];
  const float* w_ih   = (const float*)d_in[9];
  const float* w_hh   = (const float*)d_in[10];
  const float* b_ih   = (const float*)d_in[11];
  const float* b_hh   = (const float*)d_in[12];
  const float* w_pr1  = (const float*)d_in[13];
  const float* b_pr1  = (const float*)d_in[14];
  const float* w_pr2  = (const float*)d_in[15];
  const float* b_pr2  = (const float*)d_in[16];
  const float* w_prm  = (const float*)d_in[17];
  const float* b_prm  = (const float*)d_in[18];
  const float* w_prv  = (const float*)d_in[19];
  const float* b_prv  = (const float*)d_in[20];
  const float* w_po1  = (const float*)d_in[21];
  const float* b_po1  = (const float*)d_in[22];
  const float* w_po2  = (const float*)d_in[23];
  const float* b_po2  = (const float*)d_in[24];
  const float* w_pom  = (const float*)d_in[25];
  const float* b_pom  = (const float*)d_in[26];
  const float* w_pov  = (const float*)d_in[27];
  const float* b_pov  = (const float*)d_in[28];

  unsigned short* B1 = (unsigned short*)d_ws;                       // 65536x256 bf16
  unsigned short* WT = (unsigned short*)((char*)d_ws + B1_BYTES);   // shuffled tiles

  ShufArgs sa;
  const float* srcs[14] = {w_obs1, w_obs2, w_po1, w_po1, w_gin, w_ih, w_hh,
                           w_pr1, w_pr2, w_prm, w_prv, w_po2, w_pom, w_pov};
  const int strides[14] = {512,256,512,512,136,256,256,256,256,256,256,256,256,256};
  const int coloffs[14] = {0,0,256,0,0,0,0,0,0,0,0,0,0,0};
  const int ktl[14]     = {16,8,8,8,4,8,8,8,8,8,8,8,8,8};
  const int tbas[14]    = {OBS1_T,OBS2_T,PO1O_T,PO1H_T,GINS_T,IH_T,HH_T,
                           PR1_T,PR2_T,PRM_T,PRV_T,PO2_T,POM_T,POV_T};
  const int tcnt[14]    = {256,128,128,128,64,384,384,128,128,64,64,128,64,64};
  for (int i = 0; i < 14; i++){
    sa.src[i] = srcs[i]; sa.stride[i] = strides[i]; sa.coloff[i] = coloffs[i];
    sa.ktiles[i] = ktl[i]; sa.tbase[i] = tbas[i]; sa.tcnt[i] = tcnt[i];
  }
  shuffle_w<<<TOT_TILES, 64, 0, stream>>>(sa, WT);

  // obs MLP + po1_o, all in-place in B1 (rows are block-exclusive)
  big_gemm<<<1024, 256, 0, stream>>>(vis, 1, 512, WT, OBS1_T, b_obs1, 1, B1);
  big_gemm<<<1024, 256, 0, stream>>>(B1,  0, 256, WT, OBS2_T, b_obs2, 1, B1);
  big_gemm<<<1024, 256, 0, stream>>>(B1,  0, 256, WT, PO1O_T, b_po1,  0, B1);

  rssm_rnn<<<32, 1024, 0, stream>>>(WT, B1, acts, noise, w_gin, b_gin, b_ih, b_hh,
                                    b_pr1, b_pr2, b_prm, b_prv, b_po2, b_pom, b_pov,
                                    (float*)d_out);
}

// Round 3
// 6666.892 us; speedup vs baseline: 2.2595x; 1.0370x over previous
//
#include <hip/hip_runtime.h>
#include <math.h>

// ============================================================================
// RSSM forward on MI355X.
// Round 3: batch weight-tile loads. R2 post-mortem showed VGPR_Count=64 ->
// ~1-2 tiles in flight -> each of ~108 tile loads/wave/step exposed its full
// L2/L3 latency serially (50 us/step). Every stage now loads its full tile
// set into a register array (wf[8], 64 VGPRs) before the MFMA chain, giving
// 8 loads in flight per wave. GRU split into gi-phase then gh-phase with
// incremental gate evaluation to stay under the 128-VGPR / 4-waves-per-EU
// budget (16 waves/block, 1 block/CU).
// ============================================================================

using v8s   = __attribute__((ext_vector_type(8))) short;
using f32x4 = __attribute__((ext_vector_type(4))) float;

#define BN   512
#define TN   128
#define LATN 128

#define AB_S 264   // 256-col LDS activation stride (shorts)
#define SA_S 136   // 128-col stride

// pre-shuffled weight tile bases (1 tile = 16n x 32k bf16 = 1KB = 512 shorts)
#define OBS1_T 0
#define OBS2_T 256
#define PO1O_T 384
#define PO1H_T 512
#define GINS_T 640
#define IH_T   704
#define HH_T   1088
#define PR1_T  1472
#define PR2_T  1600
#define PRM_T  1728
#define PRV_T  1792
#define PO2_T  1856
#define POM_T  1984
#define POV_T  2048
#define TOT_TILES 2112

#define B1_BYTES 33554432UL          // 65536 x 256 bf16
#define KL_OFF   8388608UL           // states elements (512*128*128)

__device__ __forceinline__ unsigned short f2bf(float f){
  union { float f; unsigned u; } v; v.f = f;
  unsigned u = v.u + 0x7fffu + ((v.u >> 16) & 1u);   // RNE
  return (unsigned short)(u >> 16);
}
__device__ __forceinline__ float bf2f(unsigned short s){
  union { unsigned u; float f; } v; v.u = ((unsigned)s) << 16; return v.f;
}
__device__ __forceinline__ float sigm(float x){ return 1.f / (1.f + __expf(-x)); }
__device__ __forceinline__ float tanhx(float x){ return 1.f - 2.f/(__expf(2.f*x) + 1.f); }

#define MFMA16(a,b,c) __builtin_amdgcn_mfma_f32_16x16x32_bf16((a),(b),(c),0,0,0)
#define LDB(tIdx) (*(const v8s*)(wt + ((size_t)(tIdx))*512 + lane*8))

// ---------------------------------------------------------------------------
// Weight shuffle: f32 (N,K) row-major -> bf16 fragment-linear tiles.
// ---------------------------------------------------------------------------
struct ShufArgs {
  const float* src[14];
  int stride[14], coloff[14], ktiles[14], tbase[14], tcnt[14];
};

__global__ __launch_bounds__(64) void shuffle_w(ShufArgs sa, unsigned short* __restrict__ wt)
{
  int tile = blockIdx.x;
  int s = 0;
  while (tile >= sa.tbase[s] + sa.tcnt[s]) s++;
  int lt = tile - sa.tbase[s];
  int kt = lt % sa.ktiles[s];
  int nt = lt / sa.ktiles[s];
  int l  = threadIdx.x;
  int n  = nt*16 + (l & 15);
  int k  = sa.coloff[s] + kt*32 + (l >> 4)*8;
  const float* sp = sa.src[s] + (size_t)n * sa.stride[s] + k;
  unsigned short* dp = wt + (size_t)tile*512 + (size_t)l*8;
  #pragma unroll
  for (int j = 0; j < 8; j++) dp[j] = f2bf(sp[j]);
}

// ---------------------------------------------------------------------------
// Parallel GEMM for obs MLP / po1_o precompute.
// ---------------------------------------------------------------------------
__global__ __launch_bounds__(256) void big_gemm(
    const void* __restrict__ Ain, int aIsF32, int K,
    const unsigned short* __restrict__ wt, int tbase,
    const float* __restrict__ bias, int doRelu,
    unsigned short* __restrict__ outB)
{
  __shared__ unsigned short AL[64*AB_S];
  int tid = threadIdx.x, lane = tid & 63, wv = tid >> 6;
  int q = lane >> 4, c16 = lane & 15;
  size_t row0 = (size_t)blockIdx.x * 64;

  f32x4 acc[16];
  #pragma unroll
  for (int nt = 0; nt < 16; nt++) acc[nt] = (f32x4){0.f,0.f,0.f,0.f};

  int nchunk = K >> 8;
  int ktT    = K >> 5;
  for (int cc = 0; cc < nchunk; cc++){
    int r = tid >> 2, c0 = (tid & 3) * 64;
    if (aIsF32){
      const float* A = (const float*)Ain + (row0 + r) * (size_t)K + (size_t)cc*256 + c0;
      #pragma unroll
      for (int ii = 0; ii < 16; ii++){
        float4 x = ((const float4*)A)[ii];
        ushort4 o;
        o.x = f2bf(x.x); o.y = f2bf(x.y); o.z = f2bf(x.z); o.w = f2bf(x.w);
        *(ushort4*)&AL[r*AB_S + c0 + ii*4] = o;
      }
    } else {
      const unsigned short* A = (const unsigned short*)Ain + (row0 + r)*256 + c0;
      #pragma unroll
      for (int ii = 0; ii < 8; ii++)
        *(v8s*)&AL[r*AB_S + c0 + ii*8] = *(const v8s*)(A + ii*8);
    }
    __syncthreads();
    const unsigned short* myA = &AL[wv*16*AB_S];
    #pragma unroll
    for (int kt = 0; kt < 8; kt++){
      v8s af = *(const v8s*)&myA[c16*AB_S + kt*32 + q*8];
      #pragma unroll
      for (int nt = 0; nt < 16; nt++){
        v8s bf = *(const v8s*)(wt + ((size_t)(tbase + nt*ktT + cc*8 + kt))*512 + lane*8);
        acc[nt] = MFMA16(af, bf, acc[nt]);
      }
    }
    __syncthreads();
  }
  #pragma unroll
  for (int nt = 0; nt < 16; nt++){
    int col = nt*16 + c16;
    float b = bias[col];
    #pragma unroll
    for (int i = 0; i < 4; i++){
      float v = acc[nt][i] + b;
      if (doRelu) v = fmaxf(v, 0.f);
      outB[(row0 + wv*16 + q*4 + i)*256 + col] = f2bf(v);
    }
  }
}

// ---------------------------------------------------------------------------
// Recurrent helpers: 16 rows x 256 cols, 16 waves; wave wv owns nt = wv.
// All weight tiles for the stage are loaded into registers (wf[8]) BEFORE
// the MFMA chain so 8 loads are in flight per wave.
// ---------------------------------------------------------------------------
__device__ __forceinline__ void stage256(
    const unsigned short* __restrict__ inA,
    const unsigned short* __restrict__ wt, int tbase,
    const float* __restrict__ bias,
    unsigned short* __restrict__ outA, int lane, int wv)
{
  int q = lane >> 4, c16 = lane & 15;
  v8s wf[8];
  #pragma unroll
  for (int kt = 0; kt < 8; kt++) wf[kt] = LDB(tbase + wv*8 + kt);
  v8s af[8];
  #pragma unroll
  for (int kt = 0; kt < 8; kt++) af[kt] = *(const v8s*)&inA[c16*AB_S + kt*32 + q*8];
  f32x4 acc = (f32x4){0.f,0.f,0.f,0.f};
  #pragma unroll
  for (int kt = 0; kt < 8; kt++) acc = MFMA16(af[kt], wf[kt], acc);
  int col = wv*16 + c16;
  float b = bias[col];
  #pragma unroll
  for (int i = 0; i < 4; i++)
    outA[(q*4 + i)*AB_S + col] = f2bf(fmaxf(acc[i] + b, 0.f));
}

// posterior mid1: relu(h @ Wpo1h^T + po1_o[row,t])  (b_po1 folded into po1_o)
__device__ __forceinline__ void stage256_add(
    const unsigned short* __restrict__ inA,
    const unsigned short* __restrict__ wt, int tbase,
    const unsigned short* __restrict__ pAdd,   // + r*(TN*256) + col
    unsigned short* __restrict__ outA, int lane, int wv)
{
  int q = lane >> 4, c16 = lane & 15;
  v8s wf[8];
  #pragma unroll
  for (int kt = 0; kt < 8; kt++) wf[kt] = LDB(tbase + wv*8 + kt);
  v8s af[8];
  #pragma unroll
  for (int kt = 0; kt < 8; kt++) af[kt] = *(const v8s*)&inA[c16*AB_S + kt*32 + q*8];
  int col = wv*16 + c16;
  unsigned short pv[4];
  #pragma unroll
  for (int i = 0; i < 4; i++)
    pv[i] = __builtin_nontemporal_load(&pAdd[(size_t)(q*4 + i)*(TN*256) + col]);
  f32x4 acc = (f32x4){0.f,0.f,0.f,0.f};
  #pragma unroll
  for (int kt = 0; kt < 8; kt++) acc = MFMA16(af[kt], wf[kt], acc);
  #pragma unroll
  for (int i = 0; i < 4; i++){
    float v = acc[i] + bf2f(pv[i]);
    outA[(q*4 + i)*AB_S + col] = f2bf(fmaxf(v, 0.f));
  }
}

// heads: 16 tasks = {matrix mu/var} x {nt 0..7}; K = 256 (from AB2).
__device__ __forceinline__ void heads16(
    const unsigned short* __restrict__ AB2,
    const unsigned short* __restrict__ wt, int tM, int tV,
    const float* __restrict__ bM, const float* __restrict__ bV,
    float* __restrict__ muF, float* __restrict__ varF, int lane, int wv)
{
  int q = lane >> 4, c16 = lane & 15;
  int mtx = wv >> 3, nt = wv & 7;
  int tb  = mtx ? tV : tM;
  v8s wf[8];
  #pragma unroll
  for (int kt = 0; kt < 8; kt++) wf[kt] = LDB(tb + nt*8 + kt);
  v8s af[8];
  #pragma unroll
  for (int kt = 0; kt < 8; kt++) af[kt] = *(const v8s*)&AB2[c16*AB_S + kt*32 + q*8];
  __syncthreads();                 // everyone captured AB2 before overlay writes
  f32x4 acc = (f32x4){0.f,0.f,0.f,0.f};
  #pragma unroll
  for (int kt = 0; kt < 8; kt++) acc = MFMA16(af[kt], wf[kt], acc);
  int col = nt*16 + c16;
  float b = mtx ? bV[col] : bM[col];
  float* dst = mtx ? varF : muF;
  #pragma unroll
  for (int i = 0; i < 4; i++){
    float v = acc[i] + b;
    if (mtx) v = __expf(v) + 0.01f;
    dst[(q*4 + i)*LATN + col] = v;
  }
}

// ---------------------------------------------------------------------------
// Persistent recurrence: block g owns batch rows g*16..g*16+15 for all steps.
// 1024 threads = 16 waves (4 per SIMD).
// ---------------------------------------------------------------------------
__global__ __launch_bounds__(1024, 4) void rssm_rnn(
    const unsigned short* __restrict__ wt,
    const unsigned short* __restrict__ Pbuf,      // po1_o bf16 (B*T x 256)
    const float* __restrict__ actions, const float* __restrict__ noise,
    const float* __restrict__ w_gin,  const float* __restrict__ b_gin,
    const float* __restrict__ b_ih,   const float* __restrict__ b_hh,
    const float* __restrict__ b_pr1,  const float* __restrict__ b_pr2,
    const float* __restrict__ b_prm,  const float* __restrict__ b_prv,
    const float* __restrict__ b_po2,  const float* __restrict__ b_pom,
    const float* __restrict__ b_pov,
    float* __restrict__ out)
{
  __shared__ unsigned short sA [16*SA_S];
  __shared__ unsigned short hA [16*AB_S];
  __shared__ unsigned short AB1[16*AB_S];   // also overlaid as muq (f32 16x128)
  __shared__ unsigned short AB2[16*AB_S];   // also overlaid as varq
  __shared__ float hF   [16*256];
  __shared__ float mupF [16*LATN];
  __shared__ float varpF[16*LATN];
  __shared__ float aF   [16*8];

  float* muqF  = (float*)AB1;
  float* varqF = (float*)AB2;

  int tid = threadIdx.x, lane = tid & 63, wv = tid >> 6;
  int q = lane >> 4, c16 = lane & 15;
  int b0 = blockIdx.x * 16;

  for (int i = tid; i < 16*256; i += 1024) hF[i] = 0.f;
  for (int i = tid; i < 16*AB_S; i += 1024) hA[i] = 0;

  // ---- s0: posterior with belief = 0 -> mid1 = relu(po1_o[:, t=0]) ----
  for (int i = tid; i < 16*256; i += 1024){
    int r = i >> 8, c = i & 255;
    float v = bf2f(__builtin_nontemporal_load(&Pbuf[((size_t)(b0 + r)*TN + 0)*256 + c]));
    AB1[r*AB_S + c] = f2bf(fmaxf(v, 0.f));
  }
  __syncthreads();
  stage256(AB1, wt, PO2_T, b_po2, AB2, lane, wv);
  __syncthreads();
  heads16(AB2, wt, POM_T, POV_T, b_pom, b_pov, muqF, varqF, lane, wv);
  __syncthreads();
  {
    int r = wv;
    #pragma unroll
    for (int ii = 0; ii < 2; ii++){
      int c = lane + ii*64;
      float mq = muqF[r*LATN + c], vq = varqF[r*LATN + c];
      float ep = __builtin_nontemporal_load(&noise[((size_t)0*BN + b0 + r)*LATN + c]);
      float sv = mq + sqrtf(vq)*ep;
      sA[r*SA_S + c] = f2bf(sv);
      __builtin_nontemporal_store(sv, &out[((size_t)(b0 + r)*TN + 0)*LATN + c]);
    }
  }
  __syncthreads();

  for (int t = 0; t < TN-1; t++){
    if (tid < 128)
      aF[tid] = __builtin_nontemporal_load(
          &actions[((size_t)(b0 + (tid>>3))*127 + t)*8 + (tid & 7)]);
    __syncthreads();

    // ---- g = relu(s @ WginS^T + a @ WginA^T + b_gin) -> AB1 ----
    {
      v8s wf[4];
      #pragma unroll
      for (int kt = 0; kt < 4; kt++) wf[kt] = LDB(GINS_T + wv*4 + kt);
      v8s af[4];
      #pragma unroll
      for (int kt = 0; kt < 4; kt++) af[kt] = *(const v8s*)&sA[c16*SA_S + kt*32 + q*8];
      int col = wv*16 + c16;
      float bg = b_gin[col];
      float wa[8];
      #pragma unroll
      for (int j = 0; j < 8; j++) wa[j] = w_gin[col*136 + 128 + j];
      f32x4 acc = (f32x4){0.f,0.f,0.f,0.f};
      #pragma unroll
      for (int kt = 0; kt < 4; kt++) acc = MFMA16(af[kt], wf[kt], acc);
      #pragma unroll
      for (int i = 0; i < 4; i++){
        int r = q*4 + i;
        float v = acc[i] + bg;
        #pragma unroll
        for (int j = 0; j < 8; j++) v += aF[r*8 + j]*wa[j];
        AB1[r*AB_S + col] = f2bf(fmaxf(v, 0.f));
      }
    }
    __syncthreads();

    // ---- GRU, two phases to bound VGPRs. Wave wv owns output cols
    //      wv*16..wv*16+15; gi strips nt = s*16+wv, gh strips likewise. ----
    float hnew[4];
    {
      int col = wv*16 + c16;
      // gi phase: g from AB1
      f32x4 accI[3];
      {
        v8s ag[8];
        #pragma unroll
        for (int kt = 0; kt < 8; kt++) ag[kt] = *(const v8s*)&AB1[c16*AB_S + kt*32 + q*8];
        #pragma unroll
        for (int s = 0; s < 3; s++){
          v8s wf[8];
          #pragma unroll
          for (int kt = 0; kt < 8; kt++) wf[kt] = LDB(IH_T + (s*16 + wv)*8 + kt);
          accI[s] = (f32x4){0.f,0.f,0.f,0.f};
          #pragma unroll
          for (int kt = 0; kt < 8; kt++) accI[s] = MFMA16(ag[kt], wf[kt], accI[s]);
        }
      }
      // gh phase: h from hA (old h); incremental gate evaluation
      float rg[4], zg[4];
      {
        v8s ah[8];
        #pragma unroll
        for (int kt = 0; kt < 8; kt++) ah[kt] = *(const v8s*)&hA[c16*AB_S + kt*32 + q*8];
        // r
        {
          v8s wf[8];
          #pragma unroll
          for (int kt = 0; kt < 8; kt++) wf[kt] = LDB(HH_T + (0*16 + wv)*8 + kt);
          f32x4 a = (f32x4){0.f,0.f,0.f,0.f};
          #pragma unroll
          for (int kt = 0; kt < 8; kt++) a = MFMA16(ah[kt], wf[kt], a);
          float bir = b_ih[col], bhr = b_hh[col];
          #pragma unroll
          for (int i = 0; i < 4; i++) rg[i] = sigm(accI[0][i] + bir + a[i] + bhr);
        }
        // z
        {
          v8s wf[8];
          #pragma unroll
          for (int kt = 0; kt < 8; kt++) wf[kt] = LDB(HH_T + (1*16 + wv)*8 + kt);
          f32x4 a = (f32x4){0.f,0.f,0.f,0.f};
          #pragma unroll
          for (int kt = 0; kt < 8; kt++) a = MFMA16(ah[kt], wf[kt], a);
          float biz = b_ih[256+col], bhz = b_hh[256+col];
          #pragma unroll
          for (int i = 0; i < 4; i++) zg[i] = sigm(accI[1][i] + biz + a[i] + bhz);
        }
        // n and h_new
        {
          v8s wf[8];
          #pragma unroll
          for (int kt = 0; kt < 8; kt++) wf[kt] = LDB(HH_T + (2*16 + wv)*8 + kt);
          f32x4 a = (f32x4){0.f,0.f,0.f,0.f};
          #pragma unroll
          for (int kt = 0; kt < 8; kt++) a = MFMA16(ah[kt], wf[kt], a);
          float bin = b_ih[512+col], bhn = b_hh[512+col];
          #pragma unroll
          for (int i = 0; i < 4; i++){
            int r = q*4 + i;
            float ng = tanhx(accI[2][i] + bin + rg[i]*(a[i] + bhn));
            float ho = hF[r*256 + col];
            float hv = (1.f - zg[i])*ng + zg[i]*ho;
            hF[r*256 + col] = hv;
            hnew[i] = hv;
          }
        }
      }
    }
    __syncthreads();   // all waves' ah reads done before hA is overwritten
    {
      int col = wv*16 + c16;
      #pragma unroll
      for (int i = 0; i < 4; i++) hA[(q*4 + i)*AB_S + col] = f2bf(hnew[i]);
    }
    __syncthreads();

    // ---- prior ----
    stage256(hA,  wt, PR1_T, b_pr1, AB1, lane, wv);
    __syncthreads();
    stage256(AB1, wt, PR2_T, b_pr2, AB2, lane, wv);
    __syncthreads();
    heads16(AB2, wt, PRM_T, PRV_T, b_prm, b_prv, mupF, varpF, lane, wv);
    __syncthreads();

    // ---- posterior ----
    stage256_add(hA, wt, PO1H_T, Pbuf + ((size_t)b0*TN + (t+1))*256, AB1, lane, wv);
    __syncthreads();
    stage256(AB1, wt, PO2_T, b_po2, AB2, lane, wv);
    __syncthreads();
    heads16(AB2, wt, POM_T, POV_T, b_pom, b_pov, muqF, varqF, lane, wv);
    __syncthreads();

    // ---- sample + KL: wave wv owns batch row wv ----
    {
      int r = wv;
      float kv = 0.f;
      #pragma unroll
      for (int ii = 0; ii < 2; ii++){
        int c = lane + ii*64;
        float mq = muqF[r*LATN + c], vq = varqF[r*LATN + c];
        float ep = __builtin_nontemporal_load(
            &noise[((size_t)(t+1)*BN + b0 + r)*LATN + c]);
        float sv = mq + sqrtf(vq)*ep;
        sA[r*SA_S + c] = f2bf(sv);
        __builtin_nontemporal_store(sv, &out[((size_t)(b0 + r)*TN + (t+1))*LATN + c]);
        float mp = mupF[r*LATN + c], vp = varpF[r*LATN + c];
        float d = mq - mp;
        kv += __logf(vp) - __logf(vq) + (vq + d*d)/vp - 1.f;
      }
      #pragma unroll
      for (int m = 1; m < 64; m <<= 1) kv += __shfl_xor(kv, m, 64);
      if (lane == 0)
        __builtin_nontemporal_store(0.5f*kv, &out[KL_OFF + (size_t)(b0 + r)*127 + t]);
    }
    __syncthreads();
  }
}

// ---------------------------------------------------------------------------
extern "C" void kernel_launch(void* const* d_in, const int* in_sizes, int n_in,
                              void* d_out, int out_size, void* d_ws, size_t ws_size,
                              hipStream_t stream)
{
  (void)in_sizes; (void)n_in; (void)out_size; (void)ws_size;
  const float* vis    = (const float*)d_in[0];
  const float* acts   = (const float*)d_in[1];
  const float* noise  = (const float*)d_in[2];
  const float* w_obs1 = (const float*)d_in[3];
  const float* b_obs1 = (const float*)d_in[4];
  const float* w_obs2 = (const float*)d_in[5];
  const float* b_obs2 = (const float*)d_in[6];
  const float* w_gin  = (const float*)d_in[7];
  const float* b_gin  = (const float*)d_in[8];
  const float* w_ih   = (const float*)d_in[9];
  const float* w_hh   = (const float*)d_in[10];
  const float* b_ih   = (const float*)d_in[11];
  const float* b_hh   = (const float*)d_in[12];
  const float* w_pr1  = (const float*)d_in[13];
  const float* b_pr1  = (const float*)d_in[14];
  const float* w_pr2  = (const float*)d_in[15];
  const float* b_pr2  = (const float*)d_in[16];
  const float* w_prm  = (const float*)d_in[17];
  const float* b_prm  = (const float*)d_in[18];
  const float* w_prv  = (const float*)d_in[19];
  const float* b_prv  = (const float*)d_in[20];
  const float* w_po1  = (const float*)d_in[21];
  const float* b_po1  = (const float*)d_in[22];
  const float* w_po2  = (const float*)d_in[23];
  const float* b_po2  = (const float*)d_in[24];
  const float* w_pom  = (const float*)d_in[25];
  const float* b_pom  = (const float*)d_in[26];
  const float* w_pov  = (const float*)d_in[27];
  const float* b_pov  = (const float*)d_in[28];

  unsigned short* B1 = (unsigned short*)d_ws;                       // 65536x256 bf16
  unsigned short* WT = (unsigned short*)((char*)d_ws + B1_BYTES);   // shuffled tiles

  ShufArgs sa;
  const float* srcs[14] = {w_obs1, w_obs2, w_po1, w_po1, w_gin, w_ih, w_hh,
                           w_pr1, w_pr2, w_prm, w_prv, w_po2, w_pom, w_pov};
  const int strides[14] = {512,256,512,512,136,256,256,256,256,256,256,256,256,256};
  const int coloffs[14] = {0,0,256,0,0,0,0,0,0,0,0,0,0,0};
  const int ktl[14]     = {16,8,8,8,4,8,8,8,8,8,8,8,8,8};
  const int tbas[14]    = {OBS1_T,OBS2_T,PO1O_T,PO1H_T,GINS_T,IH_T,HH_T,
                           PR1_T,PR2_T,PRM_T,PRV_T,PO2_T,POM_T,POV_T};
  const int tcnt[14]    = {256,128,128,128,64,384,384,128,128,64,64,128,64,64};
  for (int i = 0; i < 14; i++){
    sa.src[i] = srcs[i]; sa.stride[i] = strides[i]; sa.coloff[i] = coloffs[i];
    sa.ktiles[i] = ktl[i]; sa.tbase[i] = tbas[i]; sa.tcnt[i] = tcnt[i];
  }
  shuffle_w<<<TOT_TILES, 64, 0, stream>>>(sa, WT);

  // obs MLP + po1_o, all in-place in B1 (rows are block-exclusive)
  big_gemm<<<1024, 256, 0, stream>>>(vis, 1, 512, WT, OBS1_T, b_obs1, 1, B1);
  big_gemm<<<1024, 256, 0, stream>>>(B1,  0, 256, WT, OBS2_T, b_obs2, 1, B1);
  big_gemm<<<1024, 256, 0, stream>>>(B1,  0, 256, WT, PO1O_T, b_po1,  0, B1);

  rssm_rnn<<<32, 1024, 0, stream>>>(WT, B1, acts, noise, w_gin, b_gin, b_ih, b_hh,
                                    b_pr1, b_pr2, b_prm, b_prv, b_po2, b_pom, b_pov,
                                    (float*)d_out);
}